// Round 1
// baseline (196.721 us; speedup 1.0000x reference)
//
#include <hip/hip_runtime.h>

#define N 8192
#define NF4_PER_ROW 2048  // 8192 / 4

// ---------------------------------------------------------------------------
// Kernel 1: for each pred j, find nearest gt (argmin over i of
// ||g_i||^2 + ||p_j||^2 - 2 g_i.p_j, first-index tie-break), then store
// q[j] = gts_normals[argmin] and pq[j] = preds[j].q[j] as float4 in ws.
// 4 threads cooperate per pred (interleaved gt partitions i%4==p).
// Also zeroes the output scalar.
// ---------------------------------------------------------------------------
__global__ __launch_bounds__(256) void nn_q_kernel(
        const float* __restrict__ preds,
        const float* __restrict__ gts,
        const float* __restrict__ gn,
        float4* __restrict__ qpq,
        float* __restrict__ out) {
    __shared__ float4 sg[1024];

    const int tid = threadIdx.x;
    const int pl  = tid >> 2;   // local pred 0..63
    const int p   = tid & 3;    // gt partition 0..3
    const int j   = blockIdx.x * 64 + pl;

    if (blockIdx.x == 0 && tid == 0) out[0] = 0.0f;

    const float px = preds[j * 3 + 0];
    const float py = preds[j * 3 + 1];
    const float pz = preds[j * 3 + 2];
    const float pp = px * px + py * py + pz * pz;

    float bestV = 3.4e38f;
    int   bestI = 0;

    for (int c = 0; c < 8; ++c) {
        const int base = c * 1024;
        // stage 1024 gts (x,y,z,||g||^2) into LDS; 4 per thread, coalesced-ish
        #pragma unroll
        for (int k = 0; k < 4; ++k) {
            const int t  = tid * 4 + k;
            const int gi = base + t;
            const float gx = gts[gi * 3 + 0];
            const float gy = gts[gi * 3 + 1];
            const float gz = gts[gi * 3 + 2];
            sg[t] = make_float4(gx, gy, gz, gx * gx + gy * gy + gz * gz);
        }
        __syncthreads();
        for (int t = p; t < 1024; t += 4) {
            const float4 g = sg[t];
            const float v = g.w + pp - 2.0f * (g.x * px + g.y * py + g.z * pz);
            const int gi = base + t;
            if (v < bestV) { bestV = v; bestI = gi; }  // strict < keeps first idx
        }
        __syncthreads();
    }

    // lexicographic (val, idx) reduce across the 4 partition lanes
    #pragma unroll
    for (int d = 1; d < 4; d <<= 1) {
        const float ov = __shfl_xor(bestV, d);
        const int   oi = __shfl_xor(bestI, d);
        if (ov < bestV || (ov == bestV && oi < bestI)) { bestV = ov; bestI = oi; }
    }

    if (p == 0) {
        const float qx = gn[bestI * 3 + 0];
        const float qy = gn[bestI * 3 + 1];
        const float qz = gn[bestI * 3 + 2];
        const float pq = px * qx + py * qy + pz * qz;
        qpq[j] = make_float4(qx, qy, qz, pq);
    }
}

// ---------------------------------------------------------------------------
// Kernel 2: stream A as float4, skip all-zero quads (99.7% of them), on a hit
// compute d = preds[i].q[j] - pq[j] (times A value, which is 1.0), sum d^2.
// Wave -> block reduce -> one atomicAdd per block.
// ---------------------------------------------------------------------------
__global__ __launch_bounds__(256) void loss_kernel(
        const float4* __restrict__ A4,
        const float* __restrict__ preds,
        const float4* __restrict__ qpq,
        float* __restrict__ out) {
    const int total  = N * NF4_PER_ROW;          // 16,777,216 float4s
    const int stride = gridDim.x * 256;
    float sum = 0.0f;

    for (int u = blockIdx.x * 256 + threadIdx.x; u < total; u += stride) {
        const float4 a = A4[u];
        if (a.x != 0.0f || a.y != 0.0f || a.z != 0.0f || a.w != 0.0f) {
            const int i  = u >> 11;               // row (pred i)
            const int j0 = (u & 2047) << 2;       // first col of this quad
            const float px = preds[i * 3 + 0];
            const float py = preds[i * 3 + 1];
            const float pz = preds[i * 3 + 2];
            const float av[4] = { a.x, a.y, a.z, a.w };
            #pragma unroll
            for (int k = 0; k < 4; ++k) {
                if (av[k] != 0.0f) {
                    const float4 q = qpq[j0 + k];
                    const float d = (px * q.x + py * q.y + pz * q.z - q.w) * av[k];
                    sum += d * d;
                }
            }
        }
    }

    // reduce across the 64-lane wave
    #pragma unroll
    for (int d = 32; d > 0; d >>= 1) sum += __shfl_down(sum, d);

    __shared__ float wsum[4];
    const int lane = threadIdx.x & 63;
    const int w    = threadIdx.x >> 6;
    if (lane == 0) wsum[w] = sum;
    __syncthreads();
    if (threadIdx.x == 0) {
        atomicAdd(out, wsum[0] + wsum[1] + wsum[2] + wsum[3]);
    }
}

extern "C" void kernel_launch(void* const* d_in, const int* in_sizes, int n_in,
                              void* d_out, int out_size, void* d_ws, size_t ws_size,
                              hipStream_t stream) {
    const float* preds = (const float*)d_in[0];
    const float* gts   = (const float*)d_in[1];
    const float* gn    = (const float*)d_in[2];
    const float* A     = (const float*)d_in[3];
    float* out = (float*)d_out;
    float4* qpq = (float4*)d_ws;   // 8192 * 16 B = 128 KiB scratch

    nn_q_kernel<<<N / 64, 256, 0, stream>>>(preds, gts, gn, qpq, out);
    loss_kernel<<<2048, 256, 0, stream>>>((const float4*)A, preds, qpq, out);
}

// Round 2
// 85.146 us; speedup vs baseline: 2.3104x; 2.3104x over previous
//
#include <hip/hip_runtime.h>

#define N 8192
#define NF4_PER_ROW 2048   // 8192 / 4
#define CHUNK 2048         // gts per LDS chunk (32 KiB of float4)

// ---------------------------------------------------------------------------
// Kernel 0: repack gts -> (x, y, z, ||g||^2) float4 for coalesced staging,
// and zero the output scalar.
// ---------------------------------------------------------------------------
__global__ __launch_bounds__(256) void pack_kernel(
        const float* __restrict__ gts,
        float4* __restrict__ gq,
        float* __restrict__ out) {
    const int i = blockIdx.x * 256 + threadIdx.x;
    if (i == 0) out[0] = 0.0f;
    const float x = gts[i * 3 + 0];
    const float y = gts[i * 3 + 1];
    const float z = gts[i * 3 + 2];
    gq[i] = make_float4(x, y, z, x * x + y * y + z * z);
}

// ---------------------------------------------------------------------------
// Kernel 1: nearest-gt argmin + normal gather.
// 512 blocks x 256 threads. Each WAVE owns 4 preds; its 64 lanes partition
// the gts (lane scans gt indices t = lane + 64*it from LDS). One ds_read_b128
// serves 4 distance evals. argmin uses v = ||g||^2 - 2 g.p (the ||p||^2 term
// is constant per pred and can't change the argmin). Lexicographic (v, idx)
// shuffle-reduce across the wave preserves first-index tie-breaking.
// ---------------------------------------------------------------------------
__global__ __launch_bounds__(256) void nn_q_kernel(
        const float* __restrict__ preds,
        const float4* __restrict__ gq,
        const float* __restrict__ gn,
        float4* __restrict__ qpq) {
    __shared__ float4 sg[CHUNK];

    const int tid  = threadIdx.x;
    const int lane = tid & 63;
    const int wv   = tid >> 6;                 // wave id 0..3
    const int j0   = blockIdx.x * 16 + wv * 4; // this wave's first pred

    float px[4], py[4], pz[4], bestV[4];
    int bestI[4];
    #pragma unroll
    for (int k = 0; k < 4; ++k) {
        px[k] = preds[(j0 + k) * 3 + 0];   // broadcast across wave
        py[k] = preds[(j0 + k) * 3 + 1];
        pz[k] = preds[(j0 + k) * 3 + 2];
        bestV[k] = 3.4e38f;
        bestI[k] = 0;
    }

    for (int c = 0; c < N / CHUNK; ++c) {
        #pragma unroll
        for (int s = 0; s < CHUNK / 256; ++s) {
            const int t = s * 256 + tid;
            sg[t] = gq[c * CHUNK + t];     // fully coalesced float4
        }
        __syncthreads();

        #pragma unroll 4
        for (int it = 0; it < CHUNK / 64; ++it) {
            const int t  = it * 64 + lane;
            const float4 g = sg[t];
            const int gi = c * CHUNK + t;
            #pragma unroll
            for (int k = 0; k < 4; ++k) {
                float d = g.x * px[k];
                d = fmaf(g.y, py[k], d);
                d = fmaf(g.z, pz[k], d);
                const float v = fmaf(-2.0f, d, g.w);
                if (v < bestV[k]) { bestV[k] = v; bestI[k] = gi; }
            }
        }
        __syncthreads();
    }

    // lexicographic (val, idx) min across the 64-lane wave
    #pragma unroll
    for (int d = 1; d < 64; d <<= 1) {
        #pragma unroll
        for (int k = 0; k < 4; ++k) {
            const float ov = __shfl_xor(bestV[k], d);
            const int   oi = __shfl_xor(bestI[k], d);
            if (ov < bestV[k] || (ov == bestV[k] && oi < bestI[k])) {
                bestV[k] = ov; bestI[k] = oi;
            }
        }
    }

    if (lane == 0) {
        #pragma unroll
        for (int k = 0; k < 4; ++k) {
            const int bi = bestI[k];
            const float qx = gn[bi * 3 + 0];
            const float qy = gn[bi * 3 + 1];
            const float qz = gn[bi * 3 + 2];
            const float pq = px[k] * qx + py[k] * qy + pz[k] * qz;
            qpq[j0 + k] = make_float4(qx, qy, qz, pq);
        }
    }
}

// ---------------------------------------------------------------------------
// Kernel 2: stream A as float4 (268 MB, the roofline term), skip all-zero
// quads (~99.7%), accumulate d^2 on hits, wave->block->one atomicAdd.
// ---------------------------------------------------------------------------
__global__ __launch_bounds__(256) void loss_kernel(
        const float4* __restrict__ A4,
        const float* __restrict__ preds,
        const float4* __restrict__ qpq,
        float* __restrict__ out) {
    const int total  = N * NF4_PER_ROW;      // 16,777,216 float4s
    const int stride = gridDim.x * 256;
    float sum = 0.0f;

    for (int u = blockIdx.x * 256 + threadIdx.x; u < total; u += stride) {
        const float4 a = A4[u];
        if (a.x != 0.0f || a.y != 0.0f || a.z != 0.0f || a.w != 0.0f) {
            const int i  = u >> 11;           // row (pred i)
            const int j0 = (u & 2047) << 2;   // first col of this quad
            const float px = preds[i * 3 + 0];
            const float py = preds[i * 3 + 1];
            const float pz = preds[i * 3 + 2];
            const float av[4] = { a.x, a.y, a.z, a.w };
            #pragma unroll
            for (int k = 0; k < 4; ++k) {
                if (av[k] != 0.0f) {
                    const float4 q = qpq[j0 + k];
                    const float d = (px * q.x + py * q.y + pz * q.z - q.w) * av[k];
                    sum += d * d;
                }
            }
        }
    }

    #pragma unroll
    for (int d = 32; d > 0; d >>= 1) sum += __shfl_down(sum, d);

    __shared__ float wsum[4];
    const int lane = threadIdx.x & 63;
    const int w    = threadIdx.x >> 6;
    if (lane == 0) wsum[w] = sum;
    __syncthreads();
    if (threadIdx.x == 0) {
        atomicAdd(out, wsum[0] + wsum[1] + wsum[2] + wsum[3]);
    }
}

extern "C" void kernel_launch(void* const* d_in, const int* in_sizes, int n_in,
                              void* d_out, int out_size, void* d_ws, size_t ws_size,
                              hipStream_t stream) {
    const float* preds = (const float*)d_in[0];
    const float* gts   = (const float*)d_in[1];
    const float* gn    = (const float*)d_in[2];
    const float* A     = (const float*)d_in[3];
    float* out = (float*)d_out;

    float4* qpq = (float4*)d_ws;                       // 128 KiB
    float4* gq  = (float4*)((char*)d_ws + N * 16);     // next 128 KiB

    pack_kernel<<<N / 256, 256, 0, stream>>>(gts, gq, out);
    nn_q_kernel<<<N / 16, 256, 0, stream>>>(preds, gq, gn, qpq);
    loss_kernel<<<2048, 256, 0, stream>>>((const float4*)A, preds, qpq, out);
}